// Round 1
// baseline (521.164 us; speedup 1.0000x reference)
//
#include <hip/hip_runtime.h>
#include <math.h>

// FanoCoupling on MI355X.
// out[b,c,:] = s[b,c,:] + sum_{lines l: K_l=c} g_l * (W1·s[b,I_l] + W2·s[b,J_l] + bias)
// GEMM D[m,n] (m=(b,c), n in [0,128)): n<64 -> U_c = W1·s_c ; n>=64 -> V_c = W2·s_c
// Lines: (0,1,2),(0,3,4),(0,5,6),(1,3,5),(4,1,6),(3,2,6),(4,2,5)

using bf16x8  = __attribute__((ext_vector_type(8))) __bf16;
using floatx4 = __attribute__((ext_vector_type(4))) float;

#define ROWS  112      // 16 batches * 7 colonies per block
#define LDSTR 132      // 128 + 4 pad floats (breaks pow2 stride; 2-way max = free)

// per-target-colony line tables: count, then (i, j, gate_idx) entries
__constant__ int c_nl[7]    = {0,0,1,0,1,2,3};
__constant__ int c_ei[7][3] = {{0,0,0},{0,0,0},{0,0,0},{0,0,0},{0,0,0},{1,4,0},{0,4,3}};
__constant__ int c_ej[7][3] = {{0,0,0},{0,0,0},{1,0,0},{0,0,0},{3,0,0},{3,2,0},{5,1,2}};
__constant__ int c_eg[7][3] = {{0,0,0},{0,0,0},{0,0,0},{0,0,0},{1,0,0},{3,6,0},{2,4,5}};

__device__ __forceinline__ __bf16 tobf(float f) {
    unsigned u = __builtin_bit_cast(unsigned, f);
    u = (u + 0x7FFFu + ((u >> 16) & 1u)) >> 16;   // RNE
    unsigned short s = (unsigned short)u;
    return __builtin_bit_cast(__bf16, s);
}

__device__ __forceinline__ bf16x8 cvt8(floatx4 a, floatx4 b) {
    bf16x8 r;
    r[0]=tobf(a[0]); r[1]=tobf(a[1]); r[2]=tobf(a[2]); r[3]=tobf(a[3]);
    r[4]=tobf(b[0]); r[5]=tobf(b[1]); r[6]=tobf(b[2]); r[7]=tobf(b[3]);
    return r;
}

__global__ __launch_bounds__(256, 2)
void fano_kernel(const float* __restrict__ S,
                 const float* __restrict__ W,
                 const float* __restrict__ bias,
                 const float* __restrict__ gates,
                 float* __restrict__ out)
{
    __shared__ float Dlds[ROWS * LDSTR];   // 59,136 B
    __shared__ float gsm[7];               // softmax(gates)

    const int tid  = threadIdx.x;
    const int lane = tid & 63;
    const int wave = tid >> 6;
    const int nl   = lane & 15;   // n (or m) within 16
    const int qg   = lane >> 4;   // k-quad 0..3
    const long long mbase = (long long)blockIdx.x * ROWS;

    // softmax(gates) -> LDS (covered by the syncthreads below)
    if (tid < 7) {
        float mx = gates[0];
        #pragma unroll
        for (int i = 1; i < 7; ++i) mx = fmaxf(mx, gates[i]);
        float se = 0.f, ev = 0.f;
        #pragma unroll
        for (int i = 0; i < 7; ++i) {
            float e = __expf(gates[i] - mx);
            se += e;
            if (i == tid) ev = e;
        }
        gsm[tid] = ev / se;
    }

    // ---- B-operand fragments in registers: Wb[k][n] ----
    // n<64: Wb[k][n] = W[n][k]   ; n>=64: Wb[k][n] = W[n-64][64+k]
    // lane holds n = t*16+nl, k = h*32 + qg*8 + j (j=0..7) -> 8 contiguous fp32 of a W row
    bf16x8 bfrag[8][2];
    #pragma unroll
    for (int t = 0; t < 8; ++t) {
        const int n = t * 16 + nl;
        #pragma unroll
        for (int h = 0; h < 2; ++h) {
            const int k0 = h * 32 + qg * 8;
            const float* wp = (n < 64) ? (W + n * 128 + k0)
                                       : (W + (n - 64) * 128 + 64 + k0);
            floatx4 w0 = *(const floatx4*)wp;
            floatx4 w1 = *(const floatx4*)(wp + 4);
            bfrag[t][h] = cvt8(w0, w1);
        }
    }

    // ---- MFMA phase: 7 m-tiles x 8 n-tiles, K=64 (2 mfmas) ----
    for (int mt = wave; mt < 7; mt += 4) {
        const float* arow = S + (mbase + mt * 16 + nl) * 64;
        bf16x8 afrag[2];
        #pragma unroll
        for (int h = 0; h < 2; ++h) {
            const float* ap = arow + h * 32 + qg * 8;
            floatx4 a0 = *(const floatx4*)ap;
            floatx4 a1 = *(const floatx4*)(ap + 4);
            afrag[h] = cvt8(a0, a1);
        }
        floatx4 acc[8];
        #pragma unroll
        for (int t = 0; t < 8; ++t) acc[t] = (floatx4){0.f, 0.f, 0.f, 0.f};
        #pragma unroll
        for (int h = 0; h < 2; ++h)
            #pragma unroll
            for (int t = 0; t < 8; ++t)
                acc[t] = __builtin_amdgcn_mfma_f32_16x16x32_bf16(
                             afrag[h], bfrag[t][h], acc[t], 0, 0, 0);
        // C/D layout: col = lane&15, row = (lane>>4)*4 + r
        const int row0 = mt * 16 + qg * 4;
        #pragma unroll
        for (int t = 0; t < 8; ++t) {
            const int col = t * 16 + nl;
            #pragma unroll
            for (int r = 0; r < 4; ++r)
                Dlds[(row0 + r) * LDSTR + col] = acc[t][r];
        }
    }
    __syncthreads();

    // ---- epilogue: 112 rows x 16 z-quads = 1792 units, 7 per thread ----
    #pragma unroll
    for (int it = 0; it < 7; ++it) {
        const int u   = it * 256 + tid;
        const int row = u >> 4;
        const int q   = u & 15;
        const int lb  = row / 7;          // magic-mul
        const int c   = row - lb * 7;
        const long long gbase = (mbase + row) * 64 + q * 4;
        floatx4 o = *(const floatx4*)(S + gbase);        // residual (L2-hot)
        const floatx4 bq = *(const floatx4*)(bias + q * 4);
        const int n = c_nl[c];
        const float* dbase = &Dlds[lb * 7 * LDSTR + q * 4];
        for (int e = 0; e < n; ++e) {
            const float g = gsm[c_eg[c][e]];
            floatx4 uu = *(const floatx4*)(dbase + c_ei[c][e] * LDSTR);        // U_i
            floatx4 vv = *(const floatx4*)(dbase + c_ej[c][e] * LDSTR + 64);   // V_j
            o += g * (uu + vv + bq);
        }
        *(floatx4*)(out + gbase) = o;
    }
}

extern "C" void kernel_launch(void* const* d_in, const int* in_sizes, int n_in,
                              void* d_out, int out_size, void* d_ws, size_t ws_size,
                              hipStream_t stream) {
    const float* S     = (const float*)d_in[0];   // [B,7,64]
    const float* W     = (const float*)d_in[1];   // [64,128]
    const float* bias  = (const float*)d_in[2];   // [64]
    const float* gates = (const float*)d_in[3];   // [7]
    float* out = (float*)d_out;

    const int B = in_sizes[0] / (7 * 64);         // 131072
    const int nblk = B / 16;                      // 8192 blocks, 16 batches each
    fano_kernel<<<nblk, 256, 0, stream>>>(S, W, bias, gates, out);
}

// Round 2
// 443.125 us; speedup vs baseline: 1.1761x; 1.1761x over previous
//
#include <hip/hip_runtime.h>
#include <math.h>

// FanoCoupling, round 2: persistent blocks + colony-skip GEMM.
// out[b,c,:] = s[b,c,:] + sum_{lines l: K_l=c} g_l * (W1·s[b,I_l] + W2·s[b,J_l] + bias)
// Only U_c=W1·s_c needed for c in {0,1,3,4}; V_c=W2·s_c for c in {1,2,3,5}.
// LDS D record per batch: slots [U0,U1,U3,U4,V1,V2,V3,V5] x 64 floats, stride 516.

using bf16x8  = __attribute__((ext_vector_type(8))) __bf16;
using floatx4 = __attribute__((ext_vector_type(4))) float;

#define BATCHES 16
#define DSTR    516          // 512 + 4 pad floats -> 2-way max bank aliasing

// epilogue tables: per target colony c, line count + (Uslot, Vslot, gate)
__constant__ int c_nl[7]    = {0,0,1,0,1,2,3};
__constant__ int c_us[7][3] = {{0,0,0},{0,0,0},{0,0,0},{0,0,0},{0,0,0},{1,3,0},{0,3,2}};
__constant__ int c_vs[7][3] = {{0,0,0},{0,0,0},{4,0,0},{0,0,0},{6,0,0},{6,5,0},{7,4,5}};
__constant__ int c_g [7][3] = {{0,0,0},{0,0,0},{0,0,0},{0,0,0},{1,0,0},{3,6,0},{2,4,5}};
// wave job tables: job A = (colony, U-half, slot), job B = (colony, V-half, slot)
__constant__ int wv_cA[4] = {0,1,3,4};
__constant__ int wv_cB[4] = {2,1,3,5};
__constant__ int wv_sA[4] = {0,1,2,3};
__constant__ int wv_sB[4] = {5,4,6,7};

__device__ __forceinline__ __bf16 tobf(float f) {
    unsigned u = __builtin_bit_cast(unsigned, f);
    u = (u + 0x7FFFu + ((u >> 16) & 1u)) >> 16;   // RNE
    unsigned short s = (unsigned short)u;
    return __builtin_bit_cast(__bf16, s);
}
__device__ __forceinline__ bf16x8 cvt8(floatx4 a, floatx4 b) {
    bf16x8 r;
    r[0]=tobf(a[0]); r[1]=tobf(a[1]); r[2]=tobf(a[2]); r[3]=tobf(a[3]);
    r[4]=tobf(b[0]); r[5]=tobf(b[1]); r[6]=tobf(b[2]); r[7]=tobf(b[3]);
    return r;
}

__global__ __launch_bounds__(256, 3)
void fano_kernel(const float* __restrict__ S,
                 const float* __restrict__ W,
                 const float* __restrict__ bias,
                 const float* __restrict__ gates,
                 float* __restrict__ out, int nt)
{
    __shared__ float Dlds[BATCHES * DSTR];      // 33,024 B
    __shared__ unsigned char Wb[128 * 128];     // 16,384 B bf16, XOR-swizzled 16B units
    __shared__ float Blds[64];
    __shared__ float gsm[8];

    const int tid  = threadIdx.x;
    const int lane = tid & 63;
    const int wave = tid >> 6;
    const int nl   = lane & 15;    // m (batch) / n within 16
    const int qg   = lane >> 4;    // k-quad

    const int cA = wv_cA[wave], cB = wv_cB[wave];
    const int sA = wv_sA[wave], sB = wv_sB[wave];
    const bool dup = (cA == cB);   // waves 1,2 reuse one A fragment

    // ---- prefetch first tile's A rows (overlaps W staging) ----
    long long tile = blockIdx.x;
    floatx4 aA[4], aB[4];
    {
        const float* p = S + ((long long)tile * BATCHES + nl) * 448 + cA * 64 + qg * 8;
        aA[0] = *(const floatx4*)p;      aA[1] = *(const floatx4*)(p + 4);
        aA[2] = *(const floatx4*)(p + 32); aA[3] = *(const floatx4*)(p + 36);
        if (!dup) {
            const float* q = S + ((long long)tile * BATCHES + nl) * 448 + cB * 64 + qg * 8;
            aB[0] = *(const floatx4*)q;      aB[1] = *(const floatx4*)(q + 4);
            aB[2] = *(const floatx4*)(q + 32); aB[3] = *(const floatx4*)(q + 36);
        }
    }

    // ---- stage W -> LDS bf16 once per block ----
    // B-operand B[k][n]: n<64 -> W[n][k]; n>=64 -> W[n-64][64+k]. Row n = 64 bf16
    // (128 B = 8x16B units); unit u stored at u^(n&7) -> frag reads 2-way max.
    for (int idx = tid; idx < 1024; idx += 256) {
        const int n = idx >> 3, u = idx & 7;
        const float* src = (n < 64) ? (W + n * 128 + u * 8)
                                    : (W + (n - 64) * 128 + 64 + u * 8);
        floatx4 w0 = *(const floatx4*)src;
        floatx4 w1 = *(const floatx4*)(src + 4);
        bf16x8 v = cvt8(w0, w1);
        *(bf16x8*)(Wb + n * 128 + ((u ^ (n & 7)) << 4)) = v;
    }
    if (tid < 64) Blds[tid] = bias[tid];
    if (tid < 7) {
        float mx = gates[0];
        #pragma unroll
        for (int i = 1; i < 7; ++i) mx = fmaxf(mx, gates[i]);
        float se = 0.f, ev = 0.f;
        #pragma unroll
        for (int i = 0; i < 7; ++i) {
            float e = __expf(gates[i] - mx);
            se += e;
            if (i == tid) ev = e;
        }
        gsm[tid] = ev / se;
    }
    __syncthreads();

    const int swz0 = ((qg)     ^ (nl & 7)) << 4;   // k-half 0 unit offset
    const int swz1 = ((4 + qg) ^ (nl & 7)) << 4;   // k-half 1

    for (;;) {
        const long long next = tile + gridDim.x;

        // convert prefetched A to bf16 fragments (A[m=lane&15][k=qg*8+j])
        bf16x8 afA0 = cvt8(aA[0], aA[1]);
        bf16x8 afA1 = cvt8(aA[2], aA[3]);
        bf16x8 afB0 = dup ? afA0 : cvt8(aB[0], aB[1]);
        bf16x8 afB1 = dup ? afA1 : cvt8(aB[2], aB[3]);

        floatx4 accA[4], accB[4];
        #pragma unroll
        for (int t = 0; t < 4; ++t) {
            accA[t] = (floatx4){0.f,0.f,0.f,0.f};
            accB[t] = (floatx4){0.f,0.f,0.f,0.f};
        }
        #pragma unroll
        for (int t = 0; t < 4; ++t) {
            const unsigned char* r0 = Wb + (t * 16 + nl) * 128;        // U tiles n<64
            const unsigned char* r1 = Wb + ((t + 4) * 16 + nl) * 128;  // V tiles n>=64
            accA[t] = __builtin_amdgcn_mfma_f32_16x16x32_bf16(afA0, *(const bf16x8*)(r0 + swz0), accA[t], 0,0,0);
            accA[t] = __builtin_amdgcn_mfma_f32_16x16x32_bf16(afA1, *(const bf16x8*)(r0 + swz1), accA[t], 0,0,0);
            accB[t] = __builtin_amdgcn_mfma_f32_16x16x32_bf16(afB0, *(const bf16x8*)(r1 + swz0), accB[t], 0,0,0);
            accB[t] = __builtin_amdgcn_mfma_f32_16x16x32_bf16(afB1, *(const bf16x8*)(r1 + swz1), accB[t], 0,0,0);
        }
        // C/D layout: col=lane&15 (=n), row=qg*4+r (=batch)
        #pragma unroll
        for (int t = 0; t < 4; ++t)
            #pragma unroll
            for (int r = 0; r < 4; ++r) {
                Dlds[(qg * 4 + r) * DSTR + sA * 64 + t * 16 + nl] = accA[t][r];
                Dlds[(qg * 4 + r) * DSTR + sB * 64 + t * 16 + nl] = accB[t][r];
            }
        __syncthreads();

        // prefetch next tile's A while epilogue runs (HBM latency overlap)
        const bool more = (next < (long long)nt);
        if (more) {
            const float* p = S + (next * BATCHES + nl) * 448 + cA * 64 + qg * 8;
            aA[0] = *(const floatx4*)p;      aA[1] = *(const floatx4*)(p + 4);
            aA[2] = *(const floatx4*)(p + 32); aA[3] = *(const floatx4*)(p + 36);
            if (!dup) {
                const float* q = S + (next * BATCHES + nl) * 448 + cB * 64 + qg * 8;
                aB[0] = *(const floatx4*)q;      aB[1] = *(const floatx4*)(q + 4);
                aB[2] = *(const floatx4*)(q + 32); aB[3] = *(const floatx4*)(q + 36);
            }
        }

        // ---- epilogue: 112 rows x 16 z-quads, 7 units/thread ----
        const long long obase = tile * (BATCHES * 7 * 64);
        #pragma unroll
        for (int it = 0; it < 7; ++it) {
            const int u   = it * 256 + tid;
            const int row = u >> 4;          // (b,c) row in tile
            const int q   = u & 15;          // z-quad
            const int b   = row / 7;
            const int c   = row - b * 7;
            floatx4 o  = *(const floatx4*)(S + obase + u * 4);     // residual (L2-hot)
            floatx4 bq = *(const floatx4*)(Blds + q * 4);
            const float* dbase = Dlds + b * DSTR + q * 4;
            const int n = c_nl[c];
            for (int e = 0; e < n; ++e) {
                const float g = gsm[c_g[c][e]];
                floatx4 uu = *(const floatx4*)(dbase + c_us[c][e] * 64);
                floatx4 vv = *(const floatx4*)(dbase + c_vs[c][e] * 64);
                o += g * (uu + vv + bq);
            }
            *(floatx4*)(out + obase + u * 4) = o;
        }
        __syncthreads();
        if (!more) break;
        tile = next;
    }
}

extern "C" void kernel_launch(void* const* d_in, const int* in_sizes, int n_in,
                              void* d_out, int out_size, void* d_ws, size_t ws_size,
                              hipStream_t stream) {
    const float* S     = (const float*)d_in[0];   // [B,7,64]
    const float* W     = (const float*)d_in[1];   // [64,128]
    const float* bias  = (const float*)d_in[2];   // [64]
    const float* gates = (const float*)d_in[3];   // [7]
    float* out = (float*)d_out;

    const int B  = in_sizes[0] / (7 * 64);        // 131072
    const int nt = B / BATCHES;                   // 8192 tiles
    int grid = 768;                               // 3 blocks/CU, persistent
    if (grid > nt) grid = nt;
    fano_kernel<<<grid, 256, 0, stream>>>(S, W, bias, gates, out, nt);
}